// Round 1
// baseline (593.865 us; speedup 1.0000x reference)
//
#include <hip/hip_runtime.h>

typedef __attribute__((ext_vector_type(8))) __bf16 bf16x8;
typedef __attribute__((ext_vector_type(4))) float f4;
typedef __attribute__((ext_vector_type(2))) unsigned int u32x2;

#define MFMA(a, b, c) __builtin_amdgcn_mfma_f32_16x16x32_bf16((a), (b), (c), 0, 0, 0)

// geometry: N=64 tokens, C=384, H=12 heads, HD=32, NW=36 masks, B=2304 windows
// ws layout (bytes):
//   [0, 196608)         bias_t  f32 [12][64][64]
//   [196608, 1081344)   qkvp    bf16 B-fragments: frag=(nb*12+ks)*64lanes*8, nb in [0,72)
//   [1081344, 1376256)  projp   bf16 B-fragments: nb in [0,24)
//   [1376256, 1387056)  table   f32 [225][12]

__global__ void k_rpe_table(const float* __restrict__ coords,
                            const float* __restrict__ w1,
                            const float* __restrict__ b1,
                            const float* __restrict__ w2,
                            float* __restrict__ table) {
  const int p = blockIdx.x;      // 0..224
  const int lane = threadIdx.x;  // 0..63
  const float c0 = coords[p * 2 + 0], c1 = coords[p * 2 + 1];
  float hm[8];
#pragma unroll
  for (int t = 0; t < 8; ++t) {
    const int j = lane * 8 + t;
    float v = fmaf(c0, w1[j * 2 + 0], fmaf(c1, w1[j * 2 + 1], b1[j]));
    hm[t] = v > 0.f ? v : 0.f;
  }
  for (int h = 0; h < 12; ++h) {
    float s = 0.f;
#pragma unroll
    for (int t = 0; t < 8; ++t) s = fmaf(hm[t], w2[h * 512 + lane * 8 + t], s);
    for (int off = 32; off >= 1; off >>= 1) s += __shfl_xor(s, off);
    if (lane == 0) table[p * 12 + h] = s;
  }
}

__global__ void k_bias_gather(const float* __restrict__ table,
                              const int* __restrict__ rel,
                              float* __restrict__ bias_t) {
  const int idx = blockIdx.x * 256 + threadIdx.x;  // 49152 total
  const int h = idx >> 12;
  const int r = idx & 4095;
  bias_t[idx] = table[rel[r] * 12 + h];
}

__global__ void k_pack_w(const float* __restrict__ qkv_w,
                         const float* __restrict__ proj_w,
                         __bf16* __restrict__ qkvp,
                         __bf16* __restrict__ projp) {
  const int gid = blockIdx.x * 256 + threadIdx.x;  // 73728 total
  const int frag = gid >> 6, lane = gid & 63;
  const int lr = lane & 15, lhi = lane >> 4;
  const float* src;
  __bf16* dst;
  if (frag < 864) {
    const int nb = frag / 12, ks = frag % 12;
    src = qkv_w + (nb * 16 + lr) * 384 + ks * 32 + lhi * 8;
    dst = qkvp + (size_t)frag * 512 + lane * 8;
  } else {
    const int f2 = frag - 864;
    const int nb = f2 / 12, ks = f2 % 12;
    src = proj_w + (nb * 16 + lr) * 384 + ks * 32 + lhi * 8;
    dst = projp + (size_t)f2 * 512 + lane * 8;
  }
#pragma unroll
  for (int j = 0; j < 8; ++j) dst[j] = (__bf16)src[j];
}

// LDS map (bytes):
//   [0, 49152)        xs: x as bf16, 64 rows * 768B, byte ^= ((row&7)<<4) swizzle
//   [49152, 108544)   4 wave-private buffers of 14848B:
//                        +0     qs   64 rows * 80B   (also reused as ps: 64 rows * 144B)
//                        +5120  ks   64 rows * 80B
//                        +10240 v^T  32 rows * 144B
//   [108544, 158720)  attn_out bf16: 64 rows * 784B
__global__ __launch_bounds__(256, 1) void k_wattn(
    const float* __restrict__ x, const float* __restrict__ mask,
    const float* __restrict__ q_bias, const float* __restrict__ v_bias,
    const float* __restrict__ proj_b, const float* __restrict__ bias_t,
    const bf16x8* __restrict__ qkvp, const bf16x8* __restrict__ projp,
    float* __restrict__ out) {
  __shared__ __align__(16) char lds[158720];
  const int tid = threadIdx.x;
  const int b = blockIdx.x;

  // ---- Phase A: stage X (64x384) as bf16 into LDS ----
  {
    const f4* xp = (const f4*)(x + (size_t)b * (64 * 384));
#pragma unroll
    for (int it = 0; it < 24; ++it) {
      const int idx = tid + it * 256;  // 0..6143 float4's
      const int row = idx / 96;
      const int c4 = idx % 96;
      f4 v = xp[idx];
      unsigned short h0 = __builtin_bit_cast(unsigned short, (__bf16)v[0]);
      unsigned short h1 = __builtin_bit_cast(unsigned short, (__bf16)v[1]);
      unsigned short h2 = __builtin_bit_cast(unsigned short, (__bf16)v[2]);
      unsigned short h3 = __builtin_bit_cast(unsigned short, (__bf16)v[3]);
      u32x2 pk;
      pk[0] = (unsigned)h0 | ((unsigned)h1 << 16);
      pk[1] = (unsigned)h2 | ((unsigned)h3 << 16);
      *(u32x2*)(lds + row * 768 + ((c4 * 8) ^ ((row & 7) << 4))) = pk;
    }
  }
  __syncthreads();

  const int w = tid >> 6, lane = tid & 63;
  const int lr = lane & 15, lhi = lane >> 4;
  char* wb = lds + 49152 + w * 14848;
  const int mb = b % 36;
  const float scale = 0.17677669529663687f;  // 32^-0.5
  const f4 fz = {0.f, 0.f, 0.f, 0.f};

  for (int hi = 0; hi < 3; ++hi) {
    const int h = w * 3 + hi;
    // ---- fused q,k,v projection: 64x32 each, K=384 ----
    f4 aq[4][2], ak[4][2], av[4][2];
#pragma unroll
    for (int mi = 0; mi < 4; ++mi)
#pragma unroll
      for (int nj = 0; nj < 2; ++nj) {
        aq[mi][nj] = fz;
        ak[mi][nj] = fz;
        av[mi][nj] = fz;
      }
    const bf16x8* fq = qkvp + (h * 2) * 12 * 64 + lane;
    const bf16x8* fk = qkvp + (24 + h * 2) * 12 * 64 + lane;
    const bf16x8* fv = qkvp + (48 + h * 2) * 12 * 64 + lane;
    for (int ks = 0; ks < 12; ++ks) {
      bf16x8 a[4];
#pragma unroll
      for (int mi = 0; mi < 4; ++mi) {
        const int row = mi * 16 + lr;
        a[mi] = *(const bf16x8*)(lds + row * 768 +
                                 ((ks * 64 + lhi * 16) ^ ((row & 7) << 4)));
      }
      const bf16x8 bq0 = fq[ks * 64], bq1 = fq[(12 + ks) * 64];
      const bf16x8 bk0 = fk[ks * 64], bk1 = fk[(12 + ks) * 64];
      const bf16x8 bv0 = fv[ks * 64], bv1 = fv[(12 + ks) * 64];
#pragma unroll
      for (int mi = 0; mi < 4; ++mi) {
        aq[mi][0] = MFMA(a[mi], bq0, aq[mi][0]);
        aq[mi][1] = MFMA(a[mi], bq1, aq[mi][1]);
        ak[mi][0] = MFMA(a[mi], bk0, ak[mi][0]);
        ak[mi][1] = MFMA(a[mi], bk1, ak[mi][1]);
        av[mi][0] = MFMA(a[mi], bv0, av[mi][0]);
        av[mi][1] = MFMA(a[mi], bv1, av[mi][1]);
      }
    }
    // scatter q (bias+scale), k, v^T (bias) into wave-private LDS
    const float qb0 = q_bias[h * 32 + lr], qb1 = q_bias[h * 32 + 16 + lr];
    const float vb0 = v_bias[h * 32 + lr], vb1 = v_bias[h * 32 + 16 + lr];
#pragma unroll
    for (int mi = 0; mi < 4; ++mi) {
#pragma unroll
      for (int r = 0; r < 4; ++r) {
        const int row = mi * 16 + lhi * 4 + r;
        *(__bf16*)(wb + row * 80 + lr * 2) = (__bf16)((aq[mi][0][r] + qb0) * scale);
        *(__bf16*)(wb + row * 80 + (16 + lr) * 2) = (__bf16)((aq[mi][1][r] + qb1) * scale);
        *(__bf16*)(wb + 5120 + row * 80 + lr * 2) = (__bf16)ak[mi][0][r];
        *(__bf16*)(wb + 5120 + row * 80 + (16 + lr) * 2) = (__bf16)ak[mi][1][r];
        *(__bf16*)(wb + 10240 + lr * 144 + row * 2) = (__bf16)(av[mi][0][r] + vb0);
        *(__bf16*)(wb + 10240 + (16 + lr) * 144 + row * 2) = (__bf16)(av[mi][1][r] + vb1);
      }
    }
    // ---- S = q k^T : 16 tiles, K=32 in one MFMA each ----
    bf16x8 fa[4], fb[4];
#pragma unroll
    for (int i = 0; i < 4; ++i) {
      const int rq = i * 16 + lr;
      fa[i] = *(const bf16x8*)(wb + rq * 80 + lhi * 16);
      fb[i] = *(const bf16x8*)(wb + 5120 + rq * 80 + lhi * 16);
    }
    f4 s[4][4];
#pragma unroll
    for (int mi = 0; mi < 4; ++mi)
#pragma unroll
      for (int nj = 0; nj < 4; ++nj) s[mi][nj] = MFMA(fa[mi], fb[nj], fz);
    // ---- bias + mask + softmax(rows), write P bf16 into ps (reuses q/k space) ----
    const float* bp = bias_t + h * 4096;
    const float* mp = mask + mb * 4096;
#pragma unroll
    for (int mi = 0; mi < 4; ++mi) {
#pragma unroll
      for (int r = 0; r < 4; ++r) {
        const int row = mi * 16 + lhi * 4 + r;
        float v0 = s[mi][0][r] + bp[row * 64 + lr] + mp[row * 64 + lr];
        float v1 = s[mi][1][r] + bp[row * 64 + 16 + lr] + mp[row * 64 + 16 + lr];
        float v2 = s[mi][2][r] + bp[row * 64 + 32 + lr] + mp[row * 64 + 32 + lr];
        float v3 = s[mi][3][r] + bp[row * 64 + 48 + lr] + mp[row * 64 + 48 + lr];
        float mx = fmaxf(fmaxf(v0, v1), fmaxf(v2, v3));
        mx = fmaxf(mx, __shfl_xor(mx, 1));
        mx = fmaxf(mx, __shfl_xor(mx, 2));
        mx = fmaxf(mx, __shfl_xor(mx, 4));
        mx = fmaxf(mx, __shfl_xor(mx, 8));
        v0 = __expf(v0 - mx);
        v1 = __expf(v1 - mx);
        v2 = __expf(v2 - mx);
        v3 = __expf(v3 - mx);
        float sm = v0 + v1 + v2 + v3;
        sm += __shfl_xor(sm, 1);
        sm += __shfl_xor(sm, 2);
        sm += __shfl_xor(sm, 4);
        sm += __shfl_xor(sm, 8);
        const float inv = 1.0f / sm;
        *(__bf16*)(wb + row * 144 + lr * 2) = (__bf16)(v0 * inv);
        *(__bf16*)(wb + row * 144 + (16 + lr) * 2) = (__bf16)(v1 * inv);
        *(__bf16*)(wb + row * 144 + (32 + lr) * 2) = (__bf16)(v2 * inv);
        *(__bf16*)(wb + row * 144 + (48 + lr) * 2) = (__bf16)(v3 * inv);
      }
    }
    // ---- O = P V : K=64 as two MFMA k-steps ----
    f4 o[4][2];
#pragma unroll
    for (int mi = 0; mi < 4; ++mi) {
      o[mi][0] = fz;
      o[mi][1] = fz;
    }
#pragma unroll
    for (int kh = 0; kh < 2; ++kh) {
      bf16x8 pa[4], vv[2];
#pragma unroll
      for (int mi = 0; mi < 4; ++mi) {
        const int row = mi * 16 + lr;
        pa[mi] = *(const bf16x8*)(wb + row * 144 + kh * 64 + lhi * 16);
      }
      vv[0] = *(const bf16x8*)(wb + 10240 + lr * 144 + kh * 64 + lhi * 16);
      vv[1] = *(const bf16x8*)(wb + 10240 + (16 + lr) * 144 + kh * 64 + lhi * 16);
#pragma unroll
      for (int mi = 0; mi < 4; ++mi) {
        o[mi][0] = MFMA(pa[mi], vv[0], o[mi][0]);
        o[mi][1] = MFMA(pa[mi], vv[1], o[mi][1]);
      }
    }
    // per-head output into shared attn_out tile
#pragma unroll
    for (int mi = 0; mi < 4; ++mi) {
#pragma unroll
      for (int r = 0; r < 4; ++r) {
        const int row = mi * 16 + lhi * 4 + r;
        *(__bf16*)(lds + 108544 + row * 784 + (h * 32 + lr) * 2) = (__bf16)o[mi][0][r];
        *(__bf16*)(lds + 108544 + row * 784 + (h * 32 + 16 + lr) * 2) = (__bf16)o[mi][1][r];
      }
    }
  }
  __syncthreads();

  // ---- Phase C: out = attn_out @ proj_w^T + proj_b; wave w owns dims [w*96, w*96+96) ----
  f4 po[4][6];
#pragma unroll
  for (int mi = 0; mi < 4; ++mi)
#pragma unroll
    for (int nj = 0; nj < 6; ++nj) po[mi][nj] = fz;
  const bf16x8* fw = projp + (w * 6) * 12 * 64 + lane;
  for (int ks = 0; ks < 12; ++ks) {
    bf16x8 a[4];
#pragma unroll
    for (int mi = 0; mi < 4; ++mi) {
      const int row = mi * 16 + lr;
      a[mi] = *(const bf16x8*)(lds + 108544 + row * 784 + ks * 64 + lhi * 16);
    }
    bf16x8 bw[6];
#pragma unroll
    for (int nj = 0; nj < 6; ++nj) bw[nj] = fw[(nj * 12 + ks) * 64];
#pragma unroll
    for (int mi = 0; mi < 4; ++mi)
#pragma unroll
      for (int nj = 0; nj < 6; ++nj) po[mi][nj] = MFMA(a[mi], bw[nj], po[mi][nj]);
  }
  float* ob = out + (size_t)b * (64 * 384);
#pragma unroll
  for (int nj = 0; nj < 6; ++nj) {
    const int col = w * 96 + nj * 16 + lr;
    const float pb = proj_b[col];
#pragma unroll
    for (int mi = 0; mi < 4; ++mi)
#pragma unroll
      for (int r = 0; r < 4; ++r) {
        const int row = mi * 16 + lhi * 4 + r;
        ob[row * 384 + col] = po[mi][nj][r] + pb;
      }
  }
}

extern "C" void kernel_launch(void* const* d_in, const int* in_sizes, int n_in,
                              void* d_out, int out_size, void* d_ws, size_t ws_size,
                              hipStream_t stream) {
  const float* x = (const float*)d_in[0];
  const float* mask = (const float*)d_in[1];
  const float* qkv_w = (const float*)d_in[2];
  const float* q_bias = (const float*)d_in[3];
  const float* v_bias = (const float*)d_in[4];
  const float* rpe_w1 = (const float*)d_in[5];
  const float* rpe_b1 = (const float*)d_in[6];
  const float* rpe_w2 = (const float*)d_in[7];
  const float* proj_w = (const float*)d_in[8];
  const float* proj_b = (const float*)d_in[9];
  const float* coords = (const float*)d_in[10];
  const int* rel = (const int*)d_in[11];
  float* out = (float*)d_out;

  char* ws = (char*)d_ws;
  float* bias_t = (float*)(ws);                  // 196608 B
  __bf16* qkvp = (__bf16*)(ws + 196608);         // 884736 B
  __bf16* projp = (__bf16*)(ws + 1081344);       // 294912 B
  float* table = (float*)(ws + 1376256);         // 10800 B

  k_rpe_table<<<225, 64, 0, stream>>>(coords, rpe_w1, rpe_b1, rpe_w2, table);
  k_bias_gather<<<192, 256, 0, stream>>>(table, rel, bias_t);
  k_pack_w<<<288, 256, 0, stream>>>(qkv_w, proj_w, qkvp, projp);
  k_wattn<<<2304, 256, 0, stream>>>(x, mask, q_bias, v_bias, proj_b, bias_t,
                                    (const bf16x8*)qkvp, (const bf16x8*)projp, out);
}